// Round 9
// baseline (93.103 us; speedup 1.0000x reference)
//
#include <hip/hip_runtime.h>

// Problem constants (match reference)
#define BB   8
#define CC   1024
#define TT   4096
#define HH   16
#define KK   31
#define PADD 15

#define SEGW   1024              // outputs per wave-segment
#define RPT    16                // outputs per lane (64 lanes * 16 = 1024)
#define NRD    12                // ds_read_b128 per lane window (48 floats)
#define CHUNKS 264               // 16B chunks per staged segment (1056 floats)
#define NLD    5                 // staging loads per row (4 full + 1 partial wave)

typedef float floatx4 __attribute__((ext_vector_type(4)));

// XOR swizzle p = q ^ ((q>>3)&7), verified by enumeration:
// write pattern q=lane+64i and read pattern q=4*lane+c both hit each
// 16B bank-quad exactly 8x per 64 lanes (balanced = conflict-free for b128).
__device__ __forceinline__ int swz(int q) { return q ^ ((q >> 3) & 7); }

// --- softmax over the 31 taps of each of the 16 heads -> d_ws ---
__global__ void lwconv_softmax_w(const float* __restrict__ w, float* __restrict__ wsm) {
    int h = threadIdx.x;
    if (h < HH) {
        float buf[KK];
        float m = -1e30f;
        #pragma unroll
        for (int k = 0; k < KK; ++k) { buf[k] = w[h * KK + k]; m = fmaxf(m, buf[k]); }
        float s = 0.f;
        #pragma unroll
        for (int k = 0; k < KK; ++k) { buf[k] = expf(buf[k] - m); s += buf[k]; }
        float inv = 1.f / s;
        #pragma unroll
        for (int k = 0; k < KK; ++k) wsm[h * KK + k] = buf[k] * inv;
    }
}

// --- main: 1 wave per block; block = (channel, quarter-row segment);
//     loops over 8 batch rows with a 2-deep reg->LDS pipeline, NO barriers ---
// out[t] = bias + sum_k w[k] * x[t + k - 15]
// Buffer chunk j holds floats x[seg*1024 + 4j - 16 .. +3] (OOB -> 0).
// Lane l window: chunks 4l .. 4l+11; out[a+r] uses window element r+1+k.
__global__ __launch_bounds__(64, 4) void lwconv_main(const float* __restrict__ inp,
                                                     const float* __restrict__ wsm,
                                                     const float* __restrict__ bias,
                                                     float* __restrict__ out) {
    __shared__ floatx4 buf[2][CHUNKS];        // 8448 B, wave-private block

    const int bid  = blockIdx.x;
    const int ch   = bid & (CC - 1);          // 0..1023
    const int seg  = bid >> 10;               // 0..3
    const int head = ch >> 6;                 // 64 channels per head
    const int l    = threadIdx.x;             // lane 0..63

    // uniform pre-softmaxed weights + bias (scalar regs)
    const float* wh = wsm + head * KK;
    float w[KK];
    #pragma unroll
    for (int k = 0; k < KK; ++k) w[k] = wh[k];
    const float bval = bias[head];

    floatx4 rCur[NLD];   // staged row r+1 (to be written this iter)
    floatx4 rNext[NLD];  // in-flight row r+2

    // issue the 5 staging loads of one batch row's segment into regs
    auto issue = [&](int b, floatx4 (&rg)[NLD]) {
        const float* rp = inp + ((size_t)b * CC + ch) * TT;
        #pragma unroll
        for (int i = 0; i < NLD; ++i) {
            const int j = l + 64 * i;                 // chunk index
            const int F = seg * SEGW + 4 * j - 16;    // global float offset
            floatx4 v = (floatx4)0.f;
            if ((i < 4 || l < 8) && F >= 0 && F <= TT - 4)
                v = *reinterpret_cast<const floatx4*>(rp + F);
            rg[i] = v;
        }
    };
    auto dswrite = [&](int bi, const floatx4 (&rg)[NLD]) {
        #pragma unroll
        for (int i = 0; i < NLD; ++i) {
            const int j = l + 64 * i;
            if (i < 4 || l < 8) buf[bi][swz(j)] = rg[i];
        }
    };

    // ---- prologue: rows 0 and 1 ----
    issue(0, rCur);
    issue(1, rNext);
    dswrite(0, rCur);            // drains prologue loads (once)
    #pragma unroll
    for (int i = 0; i < NLD; ++i) rCur[i] = rNext[i];

    #pragma unroll 1
    for (int r = 0; r < BB; ++r) {
        // 1) write row r+1 into the other buffer; its loads have been in
        //    flight for a full iteration, so the vmcnt wait here is free.
        if (r < BB - 1) dswrite((r + 1) & 1, rCur);
        __builtin_amdgcn_sched_barrier(0);

        // 2) fire row r+2's loads (nothing may hoist them above the wait)
        if (r < BB - 2) issue(r + 2, rNext);
        __builtin_amdgcn_sched_barrier(0);

        // 3) window: 12 ds_read_b128 from swizzled wave-private buffer
        float xv[4 * NRD];
        #pragma unroll
        for (int c = 0; c < NRD; ++c) {
            floatx4 v = buf[r & 1][swz(4 * l + c)];
            #pragma unroll
            for (int e = 0; e < 4; ++e) xv[4 * c + e] = v[e];
        }

        // 4) compute 16 outputs, store
        float acc[RPT];
        #pragma unroll
        for (int q = 0; q < RPT; ++q) acc[q] = bval;
        #pragma unroll
        for (int k = 0; k < KK; ++k) {
            #pragma unroll
            for (int q = 0; q < RPT; ++q)
                acc[q] = fmaf(xv[q + 1 + k], w[k], acc[q]);
        }

        float* orow = out + ((size_t)r * CC + ch) * TT + seg * SEGW + (l << 4);
        #pragma unroll
        for (int c2 = 0; c2 < RPT / 4; ++c2) {
            floatx4 o = { acc[4 * c2], acc[4 * c2 + 1],
                          acc[4 * c2 + 2], acc[4 * c2 + 3] };
            *reinterpret_cast<floatx4*>(orow + 4 * c2) = o;
        }

        // 5) rotate staged regs
        #pragma unroll
        for (int i = 0; i < NLD; ++i) rCur[i] = rNext[i];
    }
}

extern "C" void kernel_launch(void* const* d_in, const int* in_sizes, int n_in,
                              void* d_out, int out_size, void* d_ws, size_t ws_size,
                              hipStream_t stream) {
    const float* inp    = (const float*)d_in[0];   // (B, C, T) fp32
    const float* weight = (const float*)d_in[1];   // (H, 1, K) fp32
    const float* bias   = (const float*)d_in[2];   // (H,) fp32
    float* out = (float*)d_out;
    float* wsm = (float*)d_ws;                     // H*K softmaxed weights

    lwconv_softmax_w<<<1, 64, 0, stream>>>(weight, wsm);

    const int blocks = CC * (TT / SEGW);           // 1024 ch * 4 segs = 4096
    lwconv_main<<<blocks, 64, 0, stream>>>(inp, wsm, bias, out);
}

// Round 10
// 63.276 us; speedup vs baseline: 1.4714x; 1.4714x over previous
//
#include <hip/hip_runtime.h>

// Problem constants (match reference)
#define BB   8
#define CC   1024
#define TT   4096
#define HH   16
#define KK   31
#define PADD 15

#define RPT   16                 // outputs per thread (256 * 16 = 4096 = T)
#define NRD   12                 // ds_read_b128 per thread window (48 floats)
#define ROWCH 1024               // 16B chunks per row (4096 floats, no pad)
#define LPT   4                  // DMA loads per thread per row (1024/256)

typedef float floatx4 __attribute__((ext_vector_type(4)));
typedef const float __attribute__((address_space(1)))* gptr_t;   // global
typedef float __attribute__((address_space(3)))* lptr_t;         // LDS

// XOR swizzle p = q ^ ((q>>3)&7) — involution, bijective on [0,1024).
// Applied to the DMA SOURCE (LDS dest stays linear, as global_load_lds
// requires); reads use swz(q). Read pattern q=4*tid-4+c: per 16-lane
// phase each bank-quad gets exactly 2 lanes (2-way = free, m136).
__device__ __forceinline__ int swz(int q) { return q ^ ((q >> 3) & 7); }

// --- softmax over the 31 taps of each of the 16 heads -> d_ws ---
__global__ void lwconv_softmax_w(const float* __restrict__ w, float* __restrict__ wsm) {
    int h = threadIdx.x;
    if (h < HH) {
        float buf[KK];
        float m = -1e30f;
        #pragma unroll
        for (int k = 0; k < KK; ++k) { buf[k] = w[h * KK + k]; m = fmaxf(m, buf[k]); }
        float s = 0.f;
        #pragma unroll
        for (int k = 0; k < KK; ++k) { buf[k] = expf(buf[k] - m); s += buf[k]; }
        float inv = 1.f / s;
        #pragma unroll
        for (int k = 0; k < KK; ++k) wsm[h * KK + k] = buf[k] * inv;
    }
}

// --- main: block = 8 consecutive channels of one batch (contiguous 128KB);
//     one row per iteration, DMA double-buffer, counted vmcnt pipeline ---
// out[t] = bias + sum_k w[k] * x[t + k - 15]
__global__ __launch_bounds__(256) void lwconv_main(const float* __restrict__ inp,
                                                   const float* __restrict__ wsm,
                                                   const float* __restrict__ bias,
                                                   float* __restrict__ out) {
    __shared__ floatx4 buf[2][ROWCH];        // 32 KB -> 5 blocks/CU cap; grid=4/CU

    const int blk  = blockIdx.x;             // b*128 + g
    const int b    = blk >> 7;
    const int c0   = (blk & 127) << 3;       // 8 consecutive channels, same head
    const int head = c0 >> 6;
    const int tid  = threadIdx.x;

    const float* base  = inp + ((size_t)b * CC + c0) * TT;   // rows i=0..7 contiguous
    float*       obase = out + ((size_t)b * CC + c0) * TT;

    // stage row i into buf[i&1]: 4 DMA loads/thread, LDS linear, source swizzled
    auto stage = [&](int i) {
        const float* rp = base + (size_t)i * TT;
        #pragma unroll
        for (int j = 0; j < LPT; ++j) {
            const int d = tid + 256 * j;     // linear LDS chunk
            __builtin_amdgcn_global_load_lds((gptr_t)(rp + 4 * swz(d)),
                                             (lptr_t)(&buf[i & 1][d]), 16, 0, 0);
        }
    };

    stage(0);

    // uniform weights + bias (s_loads overlap the prologue DMA)
    const float* wh = wsm + head * KK;
    float w[KK];
    #pragma unroll
    for (int k = 0; k < KK; ++k) w[k] = wh[k];
    const float bval = bias[head];

    #pragma unroll 1
    for (int r = 0; r < BB; ++r) {
        if (r + 1 < BB) stage(r + 1);

        // In-order vmcnt retirement: leaving the 4 newest (next row's DMA)
        // guarantees row r's DMA has landed in LDS. Never drains to 0.
        asm volatile("s_waitcnt vmcnt(4)" ::: "memory");
        __builtin_amdgcn_sched_barrier(0);
        __builtin_amdgcn_s_barrier();        // buf[r&1] full for all waves

        // window: 12 ds_read_b128; zero-fill OOB chunks (tid 0 / tid 255 only)
        float xv[4 * NRD];
        #pragma unroll
        for (int c = 0; c < NRD; ++c) {
            const int q = 4 * tid - 4 + c;   // logical chunk of window pos c
            floatx4 v = (floatx4)0.f;
            if (q >= 0 && q < ROWCH) v = buf[r & 1][swz(q)];
            #pragma unroll
            for (int e = 0; e < 4; ++e) xv[4 * c + e] = v[e];
        }
        asm volatile("s_waitcnt lgkmcnt(0)" ::: "memory");   // my reads landed
        __builtin_amdgcn_sched_barrier(0);
        __builtin_amdgcn_s_barrier();        // all reads done -> buffer reusable

        // compute row r (other waves' DMA overlaps this)
        float acc[RPT];
        #pragma unroll
        for (int p = 0; p < RPT; ++p) acc[p] = bval;
        #pragma unroll
        for (int k = 0; k < KK; ++k) {
            #pragma unroll
            for (int p = 0; p < RPT; ++p)
                acc[p] = fmaf(xv[p + 1 + k], w[k], acc[p]);
        }

        float* orow = obase + (size_t)r * TT + (tid << 4);
        #pragma unroll
        for (int c2 = 0; c2 < RPT / 4; ++c2) {
            floatx4 o = { acc[4 * c2], acc[4 * c2 + 1],
                          acc[4 * c2 + 2], acc[4 * c2 + 3] };
            *reinterpret_cast<floatx4*>(orow + 4 * c2) = o;
        }
    }
}

extern "C" void kernel_launch(void* const* d_in, const int* in_sizes, int n_in,
                              void* d_out, int out_size, void* d_ws, size_t ws_size,
                              hipStream_t stream) {
    const float* inp    = (const float*)d_in[0];   // (B, C, T) fp32
    const float* weight = (const float*)d_in[1];   // (H, 1, K) fp32
    const float* bias   = (const float*)d_in[2];   // (H,) fp32
    float* out = (float*)d_out;
    float* wsm = (float*)d_ws;                     // H*K softmaxed weights

    lwconv_softmax_w<<<1, 64, 0, stream>>>(weight, wsm);

    const int blocks = BB * (CC / 8);              // 8 * 128 = 1024 = 4 blocks/CU
    lwconv_main<<<blocks, 256, 0, stream>>>(inp, wsm, bias, out);
}

// Round 11
// 61.278 us; speedup vs baseline: 1.5193x; 1.0326x over previous
//
#include <hip/hip_runtime.h>

// Problem constants (match reference)
#define BB   8
#define CC   1024
#define TT   4096
#define HH   16
#define KK   31

#define RPT  16                 // outputs per thread (256 * 16 = 4096 = T)
#define NRD  12                 // ds_read_b128 per thread window (48 floats)
#define PCH  1032               // physical 16B chunks per buffer (8 pads incl.)
#define LPT  4                  // DMA insts per thread per row (1024/256)

typedef float floatx4 __attribute__((ext_vector_type(4)));
typedef const float __attribute__((address_space(1)))* gptr_t;   // global
typedef float __attribute__((address_space(3)))* lptr_t;         // LDS

// Involution swizzle p = q ^ ((q>>3)&7); logical chunk q (holding row floats
// x[4q-16 .. 4q-13], pads q<4 / q>=1028 = zero) lives at physical chunk swz(q).
// Reads q=4*tid+c are octet-aligned -> each 8-lane phase hits 8 distinct
// bank-quads (verified by enumeration; only the wave64 2-way floor remains).
__device__ __forceinline__ int swz(int q) { return q ^ ((q >> 3) & 7); }

// --- softmax over the 31 taps of each of the 16 heads -> d_ws ---
__global__ void lwconv_softmax_w(const float* __restrict__ w, float* __restrict__ wsm) {
    int h = threadIdx.x;
    if (h < HH) {
        float buf[KK];
        float m = -1e30f;
        #pragma unroll
        for (int k = 0; k < KK; ++k) { buf[k] = w[h * KK + k]; m = fmaxf(m, buf[k]); }
        float s = 0.f;
        #pragma unroll
        for (int k = 0; k < KK; ++k) { buf[k] = expf(buf[k] - m); s += buf[k]; }
        float inv = 1.f / s;
        #pragma unroll
        for (int k = 0; k < KK; ++k) wsm[h * KK + k] = buf[k] * inv;
    }
}

// --- main: block = 8 consecutive channels of one batch (contiguous 128KB);
//     one channel-row per iteration, DMA double-buffer, depth-2 prefetch,
//     counted vmcnt (never 0 mid-loop), raw s_barrier ---
// out[t] = bias + sum_k w[k] * x[t + k - 15]
__global__ __launch_bounds__(256) void lwconv_main(const float* __restrict__ inp,
                                                   const float* __restrict__ wsm,
                                                   const float* __restrict__ bias,
                                                   float* __restrict__ out) {
    __shared__ floatx4 buf[2][PCH];          // 33,024 B -> 4 blocks/CU

    const int blk  = blockIdx.x;             // b*128 + g
    const int b    = blk >> 7;
    const int c0   = (blk & 127) << 3;       // 8 consecutive channels, same head
    const int head = c0 >> 6;
    const int tid  = threadIdx.x;

    const float* base  = inp + ((size_t)b * CC + c0) * TT;
    float*       obase = out + ((size_t)b * CC + c0) * TT;

    // stage channel-row i into buf[i&1]: LDS dest linear over physical [4,1028),
    // source address pre-swizzled (m173 pattern)
    auto stage = [&](int i) {
        const float* rp = base + (size_t)i * TT;
        #pragma unroll
        for (int j = 0; j < LPT; ++j) {
            const int p = 4 + tid + 256 * j;     // physical chunk
            const int q = swz(p);                // logical chunk staged here
            __builtin_amdgcn_global_load_lds((gptr_t)(rp + 4 * (q - 4)),
                                             (lptr_t)(&buf[i & 1][p]), 16, 0, 0);
        }
    };

    // zero the 16 pad chunks (8 per buffer) once
    if (tid < 16) {
        const int pi = tid & 7;
        const int pp = (pi < 4) ? pi : (1024 + pi);    // 0..3, 1028..1031
        buf[tid >> 3][pp] = (floatx4)0.f;
    }

    stage(0);
    stage(1);

    // uniform pre-softmaxed weights + bias (scalar loads, overlap DMA)
    const float* wh = wsm + head * KK;
    float w[KK];
    #pragma unroll
    for (int k = 0; k < KK; ++k) w[k] = wh[k];
    const float bval = bias[head];

    #pragma unroll 1
    for (int r = 0; r < BB; ++r) {
        // Counted wait: guarantee row r's 4 DMA retired (in-order vmcnt).
        // Queue at this point: [DMA r | stores r-2, DMA r+1, stores r-1] -> 12;
        // edges: r=0 -> 4 (only DMA1 after), r=1 / r=7 -> 8.
        if (r == 0)
            asm volatile("s_waitcnt vmcnt(4) lgkmcnt(0)" ::: "memory");  // + pad ds_writes
        else if (r == 1 || r == BB - 1)
            asm volatile("s_waitcnt vmcnt(8)" ::: "memory");
        else
            asm volatile("s_waitcnt vmcnt(12)" ::: "memory");
        __builtin_amdgcn_sched_barrier(0);
        __builtin_amdgcn_s_barrier();            // buf[r&1] complete for all waves
        __builtin_amdgcn_sched_barrier(0);

        // window: 12 unconditional ds_read_b128 (pads supply zeros)
        float xv[4 * NRD];
        #pragma unroll
        for (int c = 0; c < NRD; ++c) {
            floatx4 v = buf[r & 1][swz(4 * tid + c)];
            #pragma unroll
            for (int e = 0; e < 4; ++e) xv[4 * c + e] = v[e];
        }
        asm volatile("s_waitcnt lgkmcnt(0)" ::: "memory");   // my reads landed
        __builtin_amdgcn_sched_barrier(0);
        __builtin_amdgcn_s_barrier();            // ALL waves done reading buf[r&1]
        __builtin_amdgcn_sched_barrier(0);

        if (r + 2 < BB) stage(r + 2);            // depth-2 prefetch into freed buffer

        // compute row r entirely in registers, then store
        float acc[RPT];
        #pragma unroll
        for (int p = 0; p < RPT; ++p) acc[p] = bval;
        #pragma unroll
        for (int k = 0; k < KK; ++k) {
            #pragma unroll
            for (int p = 0; p < RPT; ++p)
                acc[p] = fmaf(xv[p + 1 + k], w[k], acc[p]);
        }

        float* orow = obase + (size_t)r * TT + (tid << 4);
        #pragma unroll
        for (int c2 = 0; c2 < RPT / 4; ++c2) {
            floatx4 o = { acc[4 * c2], acc[4 * c2 + 1],
                          acc[4 * c2 + 2], acc[4 * c2 + 3] };
            *reinterpret_cast<floatx4*>(orow + 4 * c2) = o;
        }
    }
}

extern "C" void kernel_launch(void* const* d_in, const int* in_sizes, int n_in,
                              void* d_out, int out_size, void* d_ws, size_t ws_size,
                              hipStream_t stream) {
    const float* inp    = (const float*)d_in[0];   // (B, C, T) fp32
    const float* weight = (const float*)d_in[1];   // (H, 1, K) fp32
    const float* bias   = (const float*)d_in[2];   // (H,) fp32
    float* out = (float*)d_out;
    float* wsm = (float*)d_ws;                     // H*K softmaxed weights

    lwconv_softmax_w<<<1, 64, 0, stream>>>(weight, wsm);

    const int blocks = BB * (CC / 8);              // 1024 = 4 blocks/CU
    lwconv_main<<<blocks, 256, 0, stream>>>(inp, wsm, bias, out);
}